// Round 1
// baseline (267.136 us; speedup 1.0000x reference)
//
#include <hip/hip_runtime.h>
#include <math.h>

#define N_TOK 4096
#define DM 512

typedef _Float16 f16x8 __attribute__((ext_vector_type(8)));
typedef _Float16 f16x4 __attribute__((ext_vector_type(4)));
typedef float f32x4 __attribute__((ext_vector_type(4)));

__device__ __forceinline__ void async_ld16(const ushort* g, ushort* l) {
  __builtin_amdgcn_global_load_lds(
      (const __attribute__((address_space(1))) void*)g,
      (__attribute__((address_space(3))) void*)l, 16, 0, 0);
}

// ---------------------------------------------------------------------------
// Fused pack + sigma.
// blocks [0,2048): pack x (1024 elems = rows 2b,2b+1) and compute sigma rows
// blocks [2048,2816): pack Wq|Wk|Wv into concatenated Wc16
// ---------------------------------------------------------------------------
__global__ __launch_bounds__(256) void pack_sigma(
    const float* __restrict__ x, const float* __restrict__ Wq,
    const float* __restrict__ Wk, const float* __restrict__ Wv,
    const float* __restrict__ Ws, _Float16* __restrict__ x16,
    _Float16* __restrict__ Wc16, float* __restrict__ sg) {
  const int b = blockIdx.x;
  const int t = threadIdx.x;
  if (b < 2048) {
    int i = b * 1024 + t * 4;
    float4 v = *(const float4*)&x[i];
    f16x4 o;
    o.x = (_Float16)v.x; o.y = (_Float16)v.y;
    o.z = (_Float16)v.z; o.w = (_Float16)v.w;
    *(f16x4*)&x16[i] = o;
    // sigma: threads [0,128) -> row 2b, [128,256) -> row 2b+1
    int col = (t * 4) & 511;
    float4 w = *(const float4*)&Ws[col];
    float p = v.x * w.x + v.y * w.y + v.z * w.z + v.w * w.w;
    __shared__ float red[256];
    red[t] = p;
    __syncthreads();
    int lt = t & 127;
    for (int off = 64; off > 0; off >>= 1) {
      if (lt < off) red[t] += red[t + off];
      __syncthreads();
    }
    if (lt == 0) {
      float s = red[t];
      sg[2 * b + (t >> 7)] = fminf(fmaxf(s, 0.001f), 1.0f);
    }
  } else {
    int e = (b - 2048) * 1024 + t * 4;
    const float* src;
    int le = e & (DM * DM - 1);
    if (e < DM * DM) src = Wq + le;
    else if (e < 2 * DM * DM) src = Wk + le;
    else src = Wv + le;
    float4 v = *(const float4*)src;
    f16x4 o;
    o.x = (_Float16)v.x; o.y = (_Float16)v.y;
    o.z = (_Float16)v.z; o.w = (_Float16)v.w;
    *(f16x4*)&Wc16[e] = o;
  }
}

// ---------------------------------------------------------------------------
// fp16 MFMA NT GEMM: C[m,n] = scale * sum_k A[m,k]*B[n,k]
// BM=BN=128, BK=32, 256 thr = 4 waves (2x2 of 64x64), 16x16x32 f16 MFMA.
// EPI=1: QKV fused (N=1536): region bn>>9 -> D0(Q16)/D1(K16)/D2(V16), fp16
// EPI=3: fp16 out: D0[gr*ldc+gc] = (f16)(acc*scale)        (raw scores)
// ---------------------------------------------------------------------------
template <int EPI>
__global__ __launch_bounds__(256) void mfma_f16(
    const _Float16* __restrict__ A, int lda, const _Float16* __restrict__ B,
    int ldb, int K, float scale, float* __restrict__ Cf, int ldc,
    _Float16* __restrict__ D0, _Float16* __restrict__ D1,
    _Float16* __restrict__ D2, float* __restrict__ Part) {
  __shared__ _Float16 lds[2 * 128 * 32];
  _Float16* Ah = lds;
  _Float16* Bh = lds + 128 * 32;

  const int t = threadIdx.x;
  const int w = t >> 6, L = t & 63;
  const int wm = (w >> 1) * 64, wn = (w & 1) * 64;
  const int row = L & 15, quad = L >> 4;
  const int bm = blockIdx.y * 128, bn = blockIdx.x * 128;
  const int kbase = blockIdx.z * K;

  f32x4 acc[4][4] = {{}};

  const int c0 = t, c1 = t + 256;
  const int r0 = c0 >> 2, o0 = (c0 & 3) * 8;
  const int r1 = r0 + 64;

  const ushort* ga0 = (const ushort*)(A + (size_t)(bm + r0) * lda + kbase + o0);
  const ushort* ga1 = (const ushort*)(A + (size_t)(bm + r1) * lda + kbase + o0);
  const ushort* gb0 = (const ushort*)(B + (size_t)(bn + r0) * ldb + kbase + o0);
  const ushort* gb1 = (const ushort*)(B + (size_t)(bn + r1) * ldb + kbase + o0);

  for (int k0 = 0; k0 < K; k0 += 32) {
    async_ld16(ga0, (ushort*)(Ah + c0 * 8));
    async_ld16(ga1, (ushort*)(Ah + c1 * 8));
    async_ld16(gb0, (ushort*)(Bh + c0 * 8));
    async_ld16(gb1, (ushort*)(Bh + c1 * 8));
    ga0 += 32; ga1 += 32; gb0 += 32; gb1 += 32;
    __syncthreads();

    f16x8 a0[4], b0[4];
#pragma unroll
    for (int i = 0; i < 4; ++i)
      a0[i] = *(const f16x8*)&Ah[(wm + i * 16 + row) * 32 + quad * 8];
#pragma unroll
    for (int j = 0; j < 4; ++j)
      b0[j] = *(const f16x8*)&Bh[(wn + j * 16 + row) * 32 + quad * 8];
#pragma unroll
    for (int i = 0; i < 4; ++i)
#pragma unroll
      for (int j = 0; j < 4; ++j)
        acc[i][j] = __builtin_amdgcn_mfma_f32_16x16x32_f16(a0[i], b0[j],
                                                           acc[i][j], 0, 0, 0);
    __syncthreads();
  }

  // epilogue: C/D layout col = lane&15, row = quad*4 + reg
  if (EPI == 1) {
    const int region = bn >> 9;  // uniform per block
    _Float16* D = (region == 0) ? D0 : ((region == 1) ? D1 : D2);
#pragma unroll
    for (int i = 0; i < 4; ++i)
#pragma unroll
      for (int j = 0; j < 4; ++j)
#pragma unroll
        for (int r = 0; r < 4; ++r) {
          int gr = bm + wm + i * 16 + quad * 4 + r;
          int nn = (bn & 511) + wn + j * 16 + row;
          D[(size_t)gr * 512 + nn] = (_Float16)acc[i][j][r];
        }
  } else {
#pragma unroll
    for (int i = 0; i < 4; ++i)
#pragma unroll
      for (int j = 0; j < 4; ++j)
#pragma unroll
        for (int r = 0; r < 4; ++r) {
          int gr = bm + wm + i * 16 + quad * 4 + r;
          int gc = bn + wn + j * 16 + row;
          D0[(size_t)gr * ldc + gc] = (_Float16)(acc[i][j][r] * scale);
        }
  }
}

// ---------------------------------------------------------------------------
// V16 [4096x512] fp16 -> VT16 [512][4096] fp16
// ---------------------------------------------------------------------------
__global__ __launch_bounds__(256) void transpose16(
    const _Float16* __restrict__ V16, _Float16* __restrict__ VT) {
  __shared__ _Float16 T[32][34];
  const int t = threadIdx.x;
  const int r = t >> 3, c4 = (t & 7) * 4;
  f16x4 v = *(const f16x4*)&V16[(size_t)(blockIdx.y * 32 + r) * 512 +
                                blockIdx.x * 32 + c4];
  T[r][c4] = v.x; T[r][c4 + 1] = v.y; T[r][c4 + 2] = v.z; T[r][c4 + 3] = v.w;
  __syncthreads();
  f16x4 o;
  o.x = T[c4][r]; o.y = T[c4 + 1][r]; o.z = T[c4 + 2][r]; o.w = T[c4 + 3][r];
  *(f16x4*)&VT[(size_t)(blockIdx.x * 32 + r) * 4096 + blockIdx.y * 32 + c4] = o;
}

// ---------------------------------------------------------------------------
// Softmax: read raw fp16 scores Sc (one row/block), fp32 math, write
// S fp32 (output) + softmaxed fp16 back into Sc in place.
// ---------------------------------------------------------------------------
__global__ __launch_bounds__(256) void softmax_kernel(
    _Float16* __restrict__ Sc, float* __restrict__ S) {
  __shared__ float red[256];
  const int t = threadIdx.x;
  _Float16* Srow16 = Sc + (size_t)blockIdx.x * N_TOK;
  float* Srow = S + (size_t)blockIdx.x * N_TOK;
  float f[16];
  float m = -INFINITY;
#pragma unroll
  for (int r = 0; r < 4; ++r) {
    f16x4 h = *(const f16x4*)&Srow16[r * 1024 + t * 4];
    f[r * 4 + 0] = (float)h.x; f[r * 4 + 1] = (float)h.y;
    f[r * 4 + 2] = (float)h.z; f[r * 4 + 3] = (float)h.w;
    m = fmaxf(m, fmaxf(fmaxf(f[r * 4], f[r * 4 + 1]),
                       fmaxf(f[r * 4 + 2], f[r * 4 + 3])));
  }
  red[t] = m;
  __syncthreads();
  for (int off = 128; off > 0; off >>= 1) {
    if (t < off) red[t] = fmaxf(red[t], red[t + off]);
    __syncthreads();
  }
  m = red[0];
  __syncthreads();
  float sum = 0.f;
#pragma unroll
  for (int i = 0; i < 16; ++i) {
    f[i] = __expf(f[i] - m);
    sum += f[i];
  }
  red[t] = sum;
  __syncthreads();
  for (int off = 128; off > 0; off >>= 1) {
    if (t < off) red[t] += red[t + off];
    __syncthreads();
  }
  const float inv = 1.0f / red[0];
#pragma unroll
  for (int r = 0; r < 4; ++r) {
    float4 o;
    o.x = f[r * 4 + 0] * inv; o.y = f[r * 4 + 1] * inv;
    o.z = f[r * 4 + 2] * inv; o.w = f[r * 4 + 3] * inv;
    *(float4*)&Srow[r * 1024 + t * 4] = o;
    f16x4 h;
    h.x = (_Float16)o.x; h.y = (_Float16)o.y;
    h.z = (_Float16)o.z; h.w = (_Float16)o.w;
    *(f16x4*)&Srow16[r * 1024 + t * 4] = h;
  }
}

// ---------------------------------------------------------------------------
// S@V GEMM (BM=64, BN=128, BK=64, 4 waves, no split-K) with P fused in as
// extra blocks. Grid (4, 64 [+1024 if FUSE_P]).
//   by <  64 : Z[64x128 tile] = Sc16 @ VT16 (fp32 direct write)
//   by >= 64 : P row i = (by-64)*4 + bx (memory-bound, overlaps the GEMM)
// LDS A layout [2][64][32] (split K-panels keep 64B-stride ds_read_b128),
// B layout [2][128][32]. global_load_lds dests stay linear in t.
// ---------------------------------------------------------------------------
template <int FUSE_P>
__global__ __launch_bounds__(256) void sv_kernel(
    const _Float16* __restrict__ A,   // Sc16 [4096][4096] (softmaxed fp16)
    const _Float16* __restrict__ B,   // VT16 [512][4096]
    float* __restrict__ C,            // Z [4096][512]
    const float* __restrict__ sigma, float* __restrict__ P) {
  __shared__ _Float16 lds[2 * 64 * 32 + 2 * 128 * 32];
  const int t = threadIdx.x;

  if (FUSE_P && blockIdx.y >= 64) {
    // ---------------- P row ----------------
    float* red = (float*)lds;
    const int i = (blockIdx.y - 64) * 4 + blockIdx.x;
    const float sg = sigma[i];
    const float inv2 = -0.5f / (sg * sg);
    const float c = rsqrtf(6.283185307179586f * sg);
    float4 g[4];
    float sum = 0.f;
#pragma unroll
    for (int r = 0; r < 4; ++r) {
      int j = r * 1024 + t * 4;
      float d0 = (float)(i - j);
      float d1 = d0 - 1.f;
      float d2 = d0 - 2.f;
      float d3 = d0 - 3.f;
      g[r].x = __expf(inv2 * d0 * d0) * c;
      g[r].y = __expf(inv2 * d1 * d1) * c;
      g[r].z = __expf(inv2 * d2 * d2) * c;
      g[r].w = __expf(inv2 * d3 * d3) * c;
      sum += g[r].x + g[r].y + g[r].z + g[r].w;
    }
    red[t] = sum;
    __syncthreads();
    for (int off = 128; off > 0; off >>= 1) {
      if (t < off) red[t] += red[t + off];
      __syncthreads();
    }
    const float inv = 1.0f / (red[0] + 1e-8f);
    float* Prow = P + (size_t)i * N_TOK;
#pragma unroll
    for (int r = 0; r < 4; ++r) {
      g[r].x *= inv; g[r].y *= inv; g[r].z *= inv; g[r].w *= inv;
      *(float4*)&Prow[r * 1024 + t * 4] = g[r];
    }
    return;
  }

  // ---------------- GEMM ----------------
  _Float16* Ah = lds;              // [2][64][32]
  _Float16* Bh = lds + 2 * 64 * 32;  // [2][128][32]

  const int w = t >> 6, L = t & 63;
  const int wm = (w >> 1) * 32, wn = (w & 1) * 64;
  const int row = L & 15, quad = L >> 4;
  const int bm = blockIdx.y * 64, bn = blockIdx.x * 128;

  f32x4 acc[2][4] = {{}};

  const int rA = t >> 2, oA = (t & 3) * 8;  // rA in [0,64)
  const ushort* ga = (const ushort*)(A + (size_t)(bm + rA) * N_TOK + oA);
  const ushort* gb0 = (const ushort*)(B + (size_t)(bn + rA) * N_TOK + oA);
  const ushort* gb1 = (const ushort*)(B + (size_t)(bn + rA + 64) * N_TOK + oA);

  for (int k0 = 0; k0 < N_TOK; k0 += 64) {
    // A: panel0 (cols k0..k0+31), panel1 (cols k0+32..k0+63)
    async_ld16(ga, (ushort*)(Ah + t * 8));
    async_ld16(ga + 32, (ushort*)(Ah + 2048 + t * 8));
    // B: panel0 rows 0-63 / 64-127, panel1 rows 0-63 / 64-127
    async_ld16(gb0, (ushort*)(Bh + t * 8));
    async_ld16(gb1, (ushort*)(Bh + (t + 256) * 8));
    async_ld16(gb0 + 32, (ushort*)(Bh + 4096 + t * 8));
    async_ld16(gb1 + 32, (ushort*)(Bh + 4096 + (t + 256) * 8));
    ga += 64; gb0 += 64; gb1 += 64;
    __syncthreads();

    f16x8 a0[2][2], b0[2][4];
#pragma unroll
    for (int kk = 0; kk < 2; ++kk) {
#pragma unroll
      for (int i = 0; i < 2; ++i)
        a0[kk][i] =
            *(const f16x8*)&Ah[kk * 2048 + (wm + i * 16 + row) * 32 + quad * 8];
#pragma unroll
      for (int j = 0; j < 4; ++j)
        b0[kk][j] =
            *(const f16x8*)&Bh[kk * 4096 + (wn + j * 16 + row) * 32 + quad * 8];
    }
#pragma unroll
    for (int kk = 0; kk < 2; ++kk)
#pragma unroll
      for (int i = 0; i < 2; ++i)
#pragma unroll
        for (int j = 0; j < 4; ++j)
          acc[i][j] = __builtin_amdgcn_mfma_f32_16x16x32_f16(
              a0[kk][i], b0[kk][j], acc[i][j], 0, 0, 0);
    __syncthreads();
  }

  // epilogue: direct fp32 write (no split-K, no partials)
#pragma unroll
  for (int i = 0; i < 2; ++i)
#pragma unroll
    for (int j = 0; j < 4; ++j)
#pragma unroll
      for (int r = 0; r < 4; ++r) {
        int gr = bm + wm + i * 16 + quad * 4 + r;
        int gc = bn + wn + j * 16 + row;
        C[(size_t)gr * 512 + gc] = acc[i][j][r];
      }
}

// ---------------------------------------------------------------------------
// Fallback P-only tail (used only if ws too small to relocate staging)
// ---------------------------------------------------------------------------
__global__ __launch_bounds__(256) void tailP(const float* __restrict__ sigma,
                                             float* __restrict__ P) {
  __shared__ float red[256];
  const int t = threadIdx.x;
  const int i = blockIdx.x;
  const float sg = sigma[i];
  const float inv2 = -0.5f / (sg * sg);
  const float c = rsqrtf(6.283185307179586f * sg);
  float4 g[4];
  float sum = 0.f;
#pragma unroll
  for (int r = 0; r < 4; ++r) {
    int j = r * 1024 + t * 4;
    float d0 = (float)(i - j);
    float d1 = d0 - 1.f;
    float d2 = d0 - 2.f;
    float d3 = d0 - 3.f;
    g[r].x = __expf(inv2 * d0 * d0) * c;
    g[r].y = __expf(inv2 * d1 * d1) * c;
    g[r].z = __expf(inv2 * d2 * d2) * c;
    g[r].w = __expf(inv2 * d3 * d3) * c;
    sum += g[r].x + g[r].y + g[r].z + g[r].w;
  }
  red[t] = sum;
  __syncthreads();
  for (int off = 128; off > 0; off >>= 1) {
    if (t < off) red[t] += red[t + off];
    __syncthreads();
  }
  const float inv = 1.0f / (red[0] + 1e-8f);
  float* Prow = P + (size_t)i * N_TOK;
#pragma unroll
  for (int r = 0; r < 4; ++r) {
    g[r].x *= inv; g[r].y *= inv; g[r].z *= inv; g[r].w *= inv;
    *(float4*)&Prow[r * 1024 + t * 4] = g[r];
  }
}

// ---------------------------------------------------------------------------
extern "C" void kernel_launch(void* const* d_in, const int* in_sizes, int n_in,
                              void* d_out, int out_size, void* d_ws,
                              size_t ws_size, hipStream_t stream) {
  const float* x = (const float*)d_in[0];
  const float* Wq = (const float*)d_in[1];
  const float* Wk = (const float*)d_in[2];
  const float* Wv = (const float*)d_in[3];
  const float* Ws = (const float*)d_in[4];

  float* out = (float*)d_out;
  float* Z = out;                        // [4096, 512]   fp32
  float* Pout = Z + (size_t)N_TOK * DM;  // [4096, 4096]  fp32
  float* S = Pout + (size_t)N_TOK * N_TOK;

  const size_t E = (size_t)N_TOK * DM;  // 2M elements

  // ws layout: x16 (4MB), Wc16 (1.5MB), sg (16KB), then fp16 staging
  _Float16* x16 = (_Float16*)d_ws;
  _Float16* Wc16 = x16 + E;
  float* sg = (float*)(Wc16 + 3 * DM * DM);
  _Float16* stage = (_Float16*)(sg + 4096);

  // staging need: Q16,K16,V16,VT16 (4*E) + Sc16 (N*N) fp16
  const size_t stage_bytes = (4 * E + (size_t)N_TOK * N_TOK) * sizeof(_Float16);
  const size_t base_bytes = (size_t)((char*)stage - (char*)d_ws);
  const bool ws_ok = ws_size >= base_bytes + stage_bytes;

  // If ws is large enough, stage in ws so the P output slice is free from the
  // start (lets P overlap the S@V GEMM). Otherwise stage inside the P slice
  // (written last) as before.
  _Float16* Q16 = ws_ok ? stage : (_Float16*)Pout;
  _Float16* K16 = Q16 + E;
  _Float16* V16 = K16 + E;
  _Float16* VT16 = V16 + E;
  _Float16* Sc16 = VT16 + E;  // [4096 x 4096] fp16: raw scores -> S16

  const dim3 blk(256);

  // 1. pack x->fp16 + sigma + pack W->fp16 (fused)
  pack_sigma<<<2816, blk, 0, stream>>>(x, Wq, Wk, Wv, Ws, x16, Wc16, sg);

  // 2. fused QKV projection: [4096x1536] = x16 @ Wcat^T -> Q16,K16,V16 fp16
  mfma_f16<1><<<dim3(12, 32), blk, 0, stream>>>(
      x16, DM, Wc16, DM, DM, 1.0f, nullptr, 0, Q16, K16, V16, nullptr);

  // 3. V -> V^T fp16
  transpose16<<<dim3(16, 128), blk, 0, stream>>>(V16, VT16);

  // 4. raw scores fp16 = Q @ K^T / sqrt(D)
  mfma_f16<3><<<dim3(32, 32), blk, 0, stream>>>(
      Q16, DM, K16, DM, DM, 1.0f / sqrtf((float)DM), nullptr, N_TOK, Sc16,
      nullptr, nullptr, nullptr);

  // 5. softmax: Sc16 -> S fp32 + S16 fp16 (in place)
  softmax_kernel<<<N_TOK, blk, 0, stream>>>(Sc16, S);

  // 6. Z = S @ V (no split-K, direct fp32 write) [+ P rows fused in]
  if (ws_ok) {
    sv_kernel<1><<<dim3(4, 64 + 1024), blk, 0, stream>>>(Sc16, VT16, Z, sg,
                                                         Pout);
  } else {
    sv_kernel<0><<<dim3(4, 64), blk, 0, stream>>>(Sc16, VT16, Z, nullptr,
                                                  nullptr);
    tailP<<<N_TOK, blk, 0, stream>>>(sg, Pout);
  }
}

// Round 2
// 244.552 us; speedup vs baseline: 1.0923x; 1.0923x over previous
//
#include <hip/hip_runtime.h>
#include <math.h>

#define N_TOK 4096
#define DM 512

typedef _Float16 f16x8 __attribute__((ext_vector_type(8)));
typedef _Float16 f16x4 __attribute__((ext_vector_type(4)));
typedef float f32x4 __attribute__((ext_vector_type(4)));

__device__ __forceinline__ void async_ld16(const ushort* g, ushort* l) {
  __builtin_amdgcn_global_load_lds(
      (const __attribute__((address_space(1))) void*)g,
      (__attribute__((address_space(3))) void*)l, 16, 0, 0);
}

template <int N>
__device__ __forceinline__ void vm_wait() {
  asm volatile("s_waitcnt vmcnt(%0)" ::"i"(N) : "memory");
}

// ---------------------------------------------------------------------------
// Fused pack + sigma.
// blocks [0,2048): pack x (1024 elems = rows 2b,2b+1) and compute sigma rows
// blocks [2048,2816): pack Wq|Wk|Wv into concatenated Wc16
// ---------------------------------------------------------------------------
__global__ __launch_bounds__(256) void pack_sigma(
    const float* __restrict__ x, const float* __restrict__ Wq,
    const float* __restrict__ Wk, const float* __restrict__ Wv,
    const float* __restrict__ Ws, _Float16* __restrict__ x16,
    _Float16* __restrict__ Wc16, float* __restrict__ sg) {
  const int b = blockIdx.x;
  const int t = threadIdx.x;
  if (b < 2048) {
    int i = b * 1024 + t * 4;
    float4 v = *(const float4*)&x[i];
    f16x4 o;
    o.x = (_Float16)v.x; o.y = (_Float16)v.y;
    o.z = (_Float16)v.z; o.w = (_Float16)v.w;
    *(f16x4*)&x16[i] = o;
    // sigma: threads [0,128) -> row 2b, [128,256) -> row 2b+1
    int col = (t * 4) & 511;
    float4 w = *(const float4*)&Ws[col];
    float p = v.x * w.x + v.y * w.y + v.z * w.z + v.w * w.w;
    __shared__ float red[256];
    red[t] = p;
    __syncthreads();
    int lt = t & 127;
    for (int off = 64; off > 0; off >>= 1) {
      if (lt < off) red[t] += red[t + off];
      __syncthreads();
    }
    if (lt == 0) {
      float s = red[t];
      sg[2 * b + (t >> 7)] = fminf(fmaxf(s, 0.001f), 1.0f);
    }
  } else {
    int e = (b - 2048) * 1024 + t * 4;
    const float* src;
    int le = e & (DM * DM - 1);
    if (e < DM * DM) src = Wq + le;
    else if (e < 2 * DM * DM) src = Wk + le;
    else src = Wv + le;
    float4 v = *(const float4*)src;
    f16x4 o;
    o.x = (_Float16)v.x; o.y = (_Float16)v.y;
    o.z = (_Float16)v.z; o.w = (_Float16)v.w;
    *(f16x4*)&Wc16[e] = o;
  }
}

// ---------------------------------------------------------------------------
// 3-deep pipelined fp16 MFMA NT GEMM: C[m,n] = scale * sum_k A[m,k]*B[n,k]
// 256 thr = 4 waves in 2x2 grid; wave tile (BM/2)x(BN/2).
// 3 LDS buffers; tile t+2 staged via global_load_lds while tile t computes;
// counted s_waitcnt vmcnt(2L) + raw s_barrier (never a full vmcnt(0) drain
// in steady state) => HBM latency hidden by ILP, works at 1 block/CU.
// EPI=1: QKV fused (N=1536): region bn>>9 -> D0(Q16)/D1(K16)/D2(V16), fp16
// EPI=3: fp16 out: D0[gr*N_TOK+gc] = (f16)(acc*scale)      (raw scores)
// EPI=2: fp32 out: Cf[gr*DM+gc] = acc; FUSE_P: blocks y>=64 emit P rows.
// ---------------------------------------------------------------------------
template <int BM, int BN, int BK, int NT, int EPI, int FUSE_P>
__global__ __launch_bounds__(256) void gemm_pipe(
    const _Float16* __restrict__ A, int lda, const _Float16* __restrict__ B,
    int ldb, float scale, float* __restrict__ Cf, _Float16* __restrict__ D0,
    _Float16* __restrict__ D1, _Float16* __restrict__ D2,
    const float* __restrict__ sigma, float* __restrict__ P) {
  constexpr int TB = (BM + BN) * BK;  // f16 per LDS buffer
  constexpr int ACH = BM * BK / 8;    // A 16B-chunks per tile
  constexpr int BCH = BN * BK / 8;
  constexpr int L = (ACH + BCH) / 256;  // global_load_lds per thread per tile
  constexpr int MI = BM / 32;           // row frags per wave (wave = BM/2 rows)
  constexpr int NJ = BN / 32;
  __shared__ _Float16 lds[3 * TB];
  const int t = threadIdx.x;

  if (FUSE_P && blockIdx.y >= 64) {
    // ---------------- P rows (4 per block), overlaps the GEMM ----------------
    float* red = (float*)lds;
    const int pidx = (blockIdx.y - 64) * 4 + blockIdx.x;  // 0..1023
    const int w = t >> 6, lane = t & 63;
#pragma unroll 1
    for (int rr = 0; rr < 4; ++rr) {
      const int i = pidx * 4 + rr;
      const float sgv = sigma[i];
      const float inv2 = -0.5f / (sgv * sgv);
      const float cc = rsqrtf(6.283185307179586f * sgv);
      float4 g[4];
      float sum = 0.f;
#pragma unroll
      for (int r = 0; r < 4; ++r) {
        int j = r * 1024 + t * 4;
        float d0 = (float)(i - j);
        float d1 = d0 - 1.f, d2 = d0 - 2.f, d3 = d0 - 3.f;
        g[r].x = __expf(inv2 * d0 * d0) * cc;
        g[r].y = __expf(inv2 * d1 * d1) * cc;
        g[r].z = __expf(inv2 * d2 * d2) * cc;
        g[r].w = __expf(inv2 * d3 * d3) * cc;
        sum += g[r].x + g[r].y + g[r].z + g[r].w;
      }
#pragma unroll
      for (int off = 32; off > 0; off >>= 1) sum += __shfl_xor(sum, off);
      if (lane == 0) red[w] = sum;
      __syncthreads();
      const float inv = 1.0f / (red[0] + red[1] + red[2] + red[3] + 1e-8f);
      float* Prow = P + (size_t)i * N_TOK;
#pragma unroll
      for (int r = 0; r < 4; ++r) {
        g[r].x *= inv; g[r].y *= inv; g[r].z *= inv; g[r].w *= inv;
        *(float4*)&Prow[r * 1024 + t * 4] = g[r];
      }
      __syncthreads();  // red[] reuse
    }
    return;
  }

  // ---------------- pipelined GEMM ----------------
  const int w = t >> 6, Ln = t & 63;
  const int wm = (w >> 1) * (BM / 2), wn = (w & 1) * (BN / 2);
  const int row = Ln & 15, quad = Ln >> 4;
  const int bm = blockIdx.y * BM, bn = blockIdx.x * BN;

  f32x4 acc[MI][NJ] = {{}};

  // per-thread global pointers for the L staging loads (chunk = t + k*256)
  const ushort* gp[L];
#pragma unroll
  for (int k = 0; k < L; ++k) {
    int c = t + k * 256;
    if (c < ACH) {
      int r = c / (BK / 8), c8 = c % (BK / 8);
      gp[k] = (const ushort*)(A + (size_t)(bm + r) * lda + c8 * 8);
    } else {
      int cb = c - ACH;
      int r = cb / (BK / 8), c8 = cb % (BK / 8);
      gp[k] = (const ushort*)(B + (size_t)(bn + r) * ldb + c8 * 8);
    }
  }

  auto stage = [&](int buf) {
    _Float16* dst = lds + buf * TB;
#pragma unroll
    for (int k = 0; k < L; ++k) {
      async_ld16(gp[k], (ushort*)(dst + (t + k * 256) * 8));
      gp[k] += BK;  // ushort* += BK elems == BK f16
    }
  };

  stage(0);  // tile 0
  stage(1);  // tile 1  (2L outstanding)

  for (int tt = 0; tt < NT; ++tt) {
    const int cur = tt % 3;
    if (tt + 2 < NT) stage((tt + 2) % 3);  // 3L outstanding
    // wait until tile tt's L loads (the oldest) have landed:
    if (tt < NT - 2) vm_wait<2 * L>();
    else if (tt == NT - 2) vm_wait<L>();
    else vm_wait<0>();
    __builtin_amdgcn_s_barrier();

    const _Float16* Ah = lds + cur * TB;
    const _Float16* Bh = Ah + BM * BK;
    f16x8 af[BK / 32][MI], bf[BK / 32][NJ];
#pragma unroll
    for (int kk = 0; kk < BK / 32; ++kk) {
#pragma unroll
      for (int i = 0; i < MI; ++i)
        af[kk][i] =
            *(const f16x8*)&Ah[(wm + i * 16 + row) * BK + kk * 32 + quad * 8];
#pragma unroll
      for (int j = 0; j < NJ; ++j)
        bf[kk][j] =
            *(const f16x8*)&Bh[(wn + j * 16 + row) * BK + kk * 32 + quad * 8];
    }
#pragma unroll
    for (int kk = 0; kk < BK / 32; ++kk)
#pragma unroll
      for (int i = 0; i < MI; ++i)
#pragma unroll
        for (int j = 0; j < NJ; ++j)
          acc[i][j] = __builtin_amdgcn_mfma_f32_16x16x32_f16(
              af[kk][i], bf[kk][j], acc[i][j], 0, 0, 0);

    asm volatile("s_waitcnt lgkmcnt(0)" ::: "memory");
    __builtin_amdgcn_s_barrier();  // safe to overwrite buf[cur] next iter
  }

  // epilogue: C/D layout col = lane&15, row = quad*4 + reg
  if constexpr (EPI == 1) {
    const int region = bn >> 9;  // uniform per block
    _Float16* D = (region == 0) ? D0 : ((region == 1) ? D1 : D2);
#pragma unroll
    for (int i = 0; i < MI; ++i)
#pragma unroll
      for (int j = 0; j < NJ; ++j)
#pragma unroll
        for (int r = 0; r < 4; ++r) {
          int gr = bm + wm + i * 16 + quad * 4 + r;
          int nn = (bn & 511) + wn + j * 16 + row;
          D[(size_t)gr * 512 + nn] = (_Float16)acc[i][j][r];
        }
  } else if constexpr (EPI == 3) {
#pragma unroll
    for (int i = 0; i < MI; ++i)
#pragma unroll
      for (int j = 0; j < NJ; ++j)
#pragma unroll
        for (int r = 0; r < 4; ++r) {
          int gr = bm + wm + i * 16 + quad * 4 + r;
          int gc = bn + wn + j * 16 + row;
          D0[(size_t)gr * N_TOK + gc] = (_Float16)(acc[i][j][r] * scale);
        }
  } else {
#pragma unroll
    for (int i = 0; i < MI; ++i)
#pragma unroll
      for (int j = 0; j < NJ; ++j)
#pragma unroll
        for (int r = 0; r < 4; ++r) {
          int gr = bm + wm + i * 16 + quad * 4 + r;
          int gc = bn + wn + j * 16 + row;
          Cf[(size_t)gr * DM + gc] = acc[i][j][r];
        }
  }
}

// ---------------------------------------------------------------------------
// V16 [4096x512] fp16 -> VT16 [512][4096] fp16
// ---------------------------------------------------------------------------
__global__ __launch_bounds__(256) void transpose16(
    const _Float16* __restrict__ V16, _Float16* __restrict__ VT) {
  __shared__ _Float16 T[32][34];
  const int t = threadIdx.x;
  const int r = t >> 3, c4 = (t & 7) * 4;
  f16x4 v = *(const f16x4*)&V16[(size_t)(blockIdx.y * 32 + r) * 512 +
                                blockIdx.x * 32 + c4];
  T[r][c4] = v.x; T[r][c4 + 1] = v.y; T[r][c4 + 2] = v.z; T[r][c4 + 3] = v.w;
  __syncthreads();
  f16x4 o;
  o.x = T[c4][r]; o.y = T[c4 + 1][r]; o.z = T[c4 + 2][r]; o.w = T[c4 + 3][r];
  *(f16x4*)&VT[(size_t)(blockIdx.x * 32 + r) * 4096 + blockIdx.y * 32 + c4] = o;
}

// ---------------------------------------------------------------------------
// Softmax: read raw fp16 scores Sc (one row/block), fp32 math, write
// S fp32 (output) + softmaxed fp16 back into Sc in place.
// ---------------------------------------------------------------------------
__global__ __launch_bounds__(256) void softmax_kernel(
    _Float16* __restrict__ Sc, float* __restrict__ S) {
  __shared__ float red[256];
  const int t = threadIdx.x;
  _Float16* Srow16 = Sc + (size_t)blockIdx.x * N_TOK;
  float* Srow = S + (size_t)blockIdx.x * N_TOK;
  float f[16];
  float m = -INFINITY;
#pragma unroll
  for (int r = 0; r < 4; ++r) {
    f16x4 h = *(const f16x4*)&Srow16[r * 1024 + t * 4];
    f[r * 4 + 0] = (float)h.x; f[r * 4 + 1] = (float)h.y;
    f[r * 4 + 2] = (float)h.z; f[r * 4 + 3] = (float)h.w;
    m = fmaxf(m, fmaxf(fmaxf(f[r * 4], f[r * 4 + 1]),
                       fmaxf(f[r * 4 + 2], f[r * 4 + 3])));
  }
  red[t] = m;
  __syncthreads();
  for (int off = 128; off > 0; off >>= 1) {
    if (t < off) red[t] = fmaxf(red[t], red[t + off]);
    __syncthreads();
  }
  m = red[0];
  __syncthreads();
  float sum = 0.f;
#pragma unroll
  for (int i = 0; i < 16; ++i) {
    f[i] = __expf(f[i] - m);
    sum += f[i];
  }
  red[t] = sum;
  __syncthreads();
  for (int off = 128; off > 0; off >>= 1) {
    if (t < off) red[t] += red[t + off];
    __syncthreads();
  }
  const float inv = 1.0f / red[0];
#pragma unroll
  for (int r = 0; r < 4; ++r) {
    float4 o;
    o.x = f[r * 4 + 0] * inv; o.y = f[r * 4 + 1] * inv;
    o.z = f[r * 4 + 2] * inv; o.w = f[r * 4 + 3] * inv;
    *(float4*)&Srow[r * 1024 + t * 4] = o;
    f16x4 h;
    h.x = (_Float16)o.x; h.y = (_Float16)o.y;
    h.z = (_Float16)o.z; h.w = (_Float16)o.w;
    *(f16x4*)&Srow16[r * 1024 + t * 4] = h;
  }
}

// ---------------------------------------------------------------------------
// Fallback P-only tail (used only if ws too small to relocate staging)
// ---------------------------------------------------------------------------
__global__ __launch_bounds__(256) void tailP(const float* __restrict__ sigma,
                                             float* __restrict__ P) {
  __shared__ float red[256];
  const int t = threadIdx.x;
  const int i = blockIdx.x;
  const float sg = sigma[i];
  const float inv2 = -0.5f / (sg * sg);
  const float c = rsqrtf(6.283185307179586f * sg);
  float4 g[4];
  float sum = 0.f;
#pragma unroll
  for (int r = 0; r < 4; ++r) {
    int j = r * 1024 + t * 4;
    float d0 = (float)(i - j);
    float d1 = d0 - 1.f, d2 = d0 - 2.f, d3 = d0 - 3.f;
    g[r].x = __expf(inv2 * d0 * d0) * c;
    g[r].y = __expf(inv2 * d1 * d1) * c;
    g[r].z = __expf(inv2 * d2 * d2) * c;
    g[r].w = __expf(inv2 * d3 * d3) * c;
    sum += g[r].x + g[r].y + g[r].z + g[r].w;
  }
  red[t] = sum;
  __syncthreads();
  for (int off = 128; off > 0; off >>= 1) {
    if (t < off) red[t] += red[t + off];
    __syncthreads();
  }
  const float inv = 1.0f / (red[0] + 1e-8f);
  float* Prow = P + (size_t)i * N_TOK;
#pragma unroll
  for (int r = 0; r < 4; ++r) {
    g[r].x *= inv; g[r].y *= inv; g[r].z *= inv; g[r].w *= inv;
    *(float4*)&Prow[r * 1024 + t * 4] = g[r];
  }
}

// ---------------------------------------------------------------------------
extern "C" void kernel_launch(void* const* d_in, const int* in_sizes, int n_in,
                              void* d_out, int out_size, void* d_ws,
                              size_t ws_size, hipStream_t stream) {
  const float* x = (const float*)d_in[0];
  const float* Wq = (const float*)d_in[1];
  const float* Wk = (const float*)d_in[2];
  const float* Wv = (const float*)d_in[3];
  const float* Ws = (const float*)d_in[4];

  float* out = (float*)d_out;
  float* Z = out;                        // [4096, 512]   fp32
  float* Pout = Z + (size_t)N_TOK * DM;  // [4096, 4096]  fp32
  float* S = Pout + (size_t)N_TOK * N_TOK;

  const size_t E = (size_t)N_TOK * DM;  // 2M elements

  // ws layout: x16 (4MB), Wc16 (1.5MB), sg (16KB), then fp16 staging
  _Float16* x16 = (_Float16*)d_ws;
  _Float16* Wc16 = x16 + E;
  float* sg = (float*)(Wc16 + 3 * DM * DM);
  _Float16* stage = (_Float16*)(sg + 4096);

  const size_t stage_bytes = (4 * E + (size_t)N_TOK * N_TOK) * sizeof(_Float16);
  const size_t base_bytes = (size_t)((char*)stage - (char*)d_ws);
  const bool ws_ok = ws_size >= base_bytes + stage_bytes;

  _Float16* Q16 = ws_ok ? stage : (_Float16*)Pout;
  _Float16* K16 = Q16 + E;
  _Float16* V16 = K16 + E;
  _Float16* VT16 = V16 + E;
  _Float16* Sc16 = VT16 + E;  // [4096 x 4096] fp16: raw scores -> S16

  const dim3 blk(256);
  const float qk_scale = 1.0f / sqrtf((float)DM);

  // 1. pack x->fp16 + sigma + pack W->fp16 (fused)
  pack_sigma<<<2816, blk, 0, stream>>>(x, Wq, Wk, Wv, Ws, x16, Wc16, sg);

  // 2. fused QKV projection: [4096x1536] = x16 @ Wcat^T -> Q16,K16,V16 fp16
  //    BM=128,BN=128,BK=32,NT=16 ; 384 blocks, 48 KB LDS
  gemm_pipe<128, 128, 32, 16, 1, 0><<<dim3(12, 32), blk, 0, stream>>>(
      x16, DM, Wc16, DM, 1.0f, nullptr, Q16, K16, V16, nullptr, nullptr);

  // 3. V -> V^T fp16
  transpose16<<<dim3(16, 128), blk, 0, stream>>>(V16, VT16);

  // 4. raw scores fp16 = Q @ K^T / sqrt(D)
  //    BM=256,BN=128 (128x64 wave tiles), 512 blocks = 2/CU, 72 KB LDS
  gemm_pipe<256, 128, 32, 16, 3, 0><<<dim3(32, 16), blk, 0, stream>>>(
      Q16, DM, K16, DM, qk_scale, nullptr, Sc16, nullptr, nullptr, nullptr,
      nullptr);

  // 5. softmax: Sc16 -> S fp32 + S16 fp16 (in place)
  softmax_kernel<<<N_TOK, blk, 0, stream>>>(Sc16, S);

  // 6. Z = S @ V (BM=64,BN=128,BK=64, pipelined, 256 blocks) + P fused
  if (ws_ok) {
    gemm_pipe<64, 128, 64, 64, 2, 1><<<dim3(4, 64 + 256), blk, 0, stream>>>(
        Sc16, N_TOK, VT16, N_TOK, 1.0f, Z, nullptr, nullptr, nullptr, sg, Pout);
  } else {
    gemm_pipe<64, 128, 64, 64, 2, 0><<<dim3(4, 64), blk, 0, stream>>>(
        Sc16, N_TOK, VT16, N_TOK, 1.0f, Z, nullptr, nullptr, nullptr, nullptr,
        nullptr);
    tailP<<<N_TOK, blk, 0, stream>>>(sg, Pout);
  }
}